// Round 2
// baseline (777.742 us; speedup 1.0000x reference)
//
#include <hip/hip_runtime.h>
#include <cstdint>
#include <cstddef>

#define NTOK 8192
#define C_ 1024
#define H_ 4096
#define E_ 8

typedef __attribute__((ext_vector_type(8))) short short8;
typedef __attribute__((ext_vector_type(4))) float f32x4;
typedef __attribute__((ext_vector_type(4))) unsigned int u32x4;

__device__ __forceinline__ uint16_t f2b(float f) {
    uint32_t x;
    __builtin_memcpy(&x, &f, 4);
    x = (x + 0x7fffu + ((x >> 16) & 1u)) >> 16;  // round-to-nearest-even
    return (uint16_t)x;
}

__device__ __forceinline__ void gld_lds16(const uint16_t* g, uint16_t* l) {
    __builtin_amdgcn_global_load_lds(
        (const __attribute__((address_space(1))) void*)g,
        (__attribute__((address_space(3))) void*)l, 16, 0, 0);
}

// ---------------- router: one wave per token, fp32 logits -> first-argmax ---
__global__ __launch_bounds__(256) void router_kernel(
    const float* __restrict__ x, const float* __restrict__ wr,
    const float* __restrict__ br, int* __restrict__ top1)
{
    int wid = threadIdx.x >> 6, lane = threadIdx.x & 63;
    int tok = blockIdx.x * 4 + wid;
    const float* xrow = x + (size_t)tok * C_;
    float acc[E_];
#pragma unroll
    for (int e = 0; e < E_; e++) acc[e] = 0.f;
#pragma unroll 4
    for (int i = 0; i < C_ / 64; i++) {
        int c = i * 64 + lane;
        float xv = xrow[c];
        const f32x4 w0 = *(const f32x4*)(wr + (size_t)c * E_);
        const f32x4 w1v = *(const f32x4*)(wr + (size_t)c * E_ + 4);
#pragma unroll
        for (int e = 0; e < 4; e++) acc[e] += xv * w0[e];
#pragma unroll
        for (int e = 0; e < 4; e++) acc[4 + e] += xv * w1v[e];
    }
#pragma unroll
    for (int off = 32; off > 0; off >>= 1) {
#pragma unroll
        for (int e = 0; e < E_; e++) acc[e] += __shfl_xor(acc[e], off, 64);
    }
    if (lane == 0) {
        float best = acc[0] + br[0];
        int bi = 0;
#pragma unroll
        for (int e = 1; e < E_; e++) {
            float v = acc[e] + br[e];
            if (v > best) { best = v; bi = e; }  // strict > == first-max (np argmax)
        }
        top1[tok] = bi;
    }
}

__global__ void zero_counts(int* counts) {
    if (threadIdx.x < E_) counts[threadIdx.x] = 0;
}

__global__ __launch_bounds__(256) void scatter_kernel(
    const int* __restrict__ top1, int* counts, int* __restrict__ idx)
{
    int t = blockIdx.x * 256 + threadIdx.x;
    int e = top1[t];
    int p = atomicAdd(&counts[e], 1);
    idx[e * NTOK + p] = t;
}

// ---------------- x fp32 -> bf16 --------------------------------------------
__global__ __launch_bounds__(256) void convert_x_kernel(
    const float* __restrict__ x, uint16_t* __restrict__ xb)
{
    size_t i = ((size_t)blockIdx.x * 256 + threadIdx.x) * 8;
    f32x4 a = *(const f32x4*)(x + i);
    f32x4 b = *(const f32x4*)(x + i + 4);
    u32x4 o;
    o.x = (uint32_t)f2b(a.x) | ((uint32_t)f2b(a.y) << 16);
    o.y = (uint32_t)f2b(a.z) | ((uint32_t)f2b(a.w) << 16);
    o.z = (uint32_t)f2b(b.x) | ((uint32_t)f2b(b.y) << 16);
    o.w = (uint32_t)f2b(b.z) | ((uint32_t)f2b(b.w) << 16);
    *(u32x4*)(xb + i) = o;
}

// ------- transpose+convert: w fp32 [E][K][N] -> wt bf16 [ez][N][K] ----------
__global__ __launch_bounds__(256) void transpose_cvt_kernel(
    const float* __restrict__ w, uint16_t* __restrict__ wt,
    int K, int N, int ebase)
{
    __shared__ uint16_t tile[64][66];  // +2 pad: conflict-free column reads
    int ez = blockIdx.z, e = ebase + ez;
    int n0 = blockIdx.x * 64, k0 = blockIdx.y * 64;
    int t = threadIdx.x;
#pragma unroll
    for (int i = 0; i < 4; i++) {
        int chunk = i * 256 + t;
        int r = chunk >> 4, c4 = chunk & 15;
        f32x4 v = *(const f32x4*)(w + (size_t)(e * K + k0 + r) * N + n0 + c4 * 4);
        uint32_t u0 = (uint32_t)f2b(v.x) | ((uint32_t)f2b(v.y) << 16);
        uint32_t u1 = (uint32_t)f2b(v.z) | ((uint32_t)f2b(v.w) << 16);
        *(uint32_t*)&tile[r][c4 * 4 + 0] = u0;
        *(uint32_t*)&tile[r][c4 * 4 + 2] = u1;
    }
    __syncthreads();
#pragma unroll
    for (int i = 0; i < 2; i++) {
        int chunk = i * 256 + t;
        int rn = chunk >> 3, ck = chunk & 7;
        uint32_t p[4];
#pragma unroll
        for (int j = 0; j < 4; j++) {
            uint32_t lo = tile[ck * 8 + 2 * j][rn];
            uint32_t hi = tile[ck * 8 + 2 * j + 1][rn];
            p[j] = lo | (hi << 16);
        }
        u32x4 v; v.x = p[0]; v.y = p[1]; v.z = p[2]; v.w = p[3];
        *(u32x4*)(wt + ((size_t)ez * N + n0 + rn) * K + k0 + ck * 8) = v;
    }
}

// ---------------- grouped GEMM (m97 structure) ------------------------------
// A: bf16 [NTOK][K] rows gathered by token id; Bt: bf16 [ez][N][K] (k contig)
// GELU=true -> Out bf16 = gelu(A@B + bias); else Out fp32 = A@B + bias
template <int K, int N, typename OutT, bool GELU>
__global__ __launch_bounds__(256) void gemm_kernel(
    const uint16_t* __restrict__ A, const uint16_t* __restrict__ Bt,
    const float* __restrict__ bias, OutT* __restrict__ Out,
    const int* __restrict__ counts, const int* __restrict__ idx, int ebase)
{
    int ez = blockIdx.z, e = ebase + ez;
    int cnt = counts[e];
    int mb = blockIdx.y;
    if (mb * 128 >= cnt) return;
    int nb = blockIdx.x;

    __shared__ __align__(16) uint16_t As[128][64];
    __shared__ __align__(16) uint16_t Bs[128][64];
    __shared__ int tok[128];

    int t = threadIdx.x;
    const int* idxe = idx + e * NTOK;
    if (t < 128) {
        int s = mb * 128 + t;
        tok[t] = idxe[(s < cnt) ? s : 0];
    }
    __syncthreads();

    int lane = t & 63, w = t >> 6;
    int wm = w >> 1, wn = w & 1;

    f32x4 acc[4][4];
#pragma unroll
    for (int mt = 0; mt < 4; mt++)
#pragma unroll
        for (int nt = 0; nt < 4; nt++) acc[mt][nt] = (f32x4)(0.f);

    const uint16_t* Bte = Bt + (size_t)ez * N * K + (size_t)nb * 128 * K;
    uint16_t* As0 = &As[0][0];
    uint16_t* Bs0 = &Bs[0][0];

    const uint16_t* aptr[4];
    const uint16_t* bptr[4];
#pragma unroll
    for (int i = 0; i < 4; i++) {
        int chunk = i * 256 + w * 64 + lane;
        int r = chunk >> 3, kc = chunk & 7;
        aptr[i] = A + (size_t)tok[r] * K + kc * 8;
        bptr[i] = Bte + (size_t)r * K + kc * 8;
    }

    for (int kt = 0; kt < K / 64; kt++) {
        int k0 = kt * 64;
#pragma unroll
        for (int i = 0; i < 4; i++)
            gld_lds16(aptr[i] + k0, As0 + (size_t)(i * 256 + w * 64) * 8);
#pragma unroll
        for (int i = 0; i < 4; i++)
            gld_lds16(bptr[i] + k0, Bs0 + (size_t)(i * 256 + w * 64) * 8);
        __syncthreads();
#pragma unroll
        for (int ks = 0; ks < 2; ks++) {
            short8 af[4], bf[4];
#pragma unroll
            for (int mt = 0; mt < 4; mt++)
                af[mt] = *(const short8*)&As[wm * 64 + mt * 16 + (lane & 15)][ks * 32 + (lane >> 4) * 8];
#pragma unroll
            for (int nt = 0; nt < 4; nt++)
                bf[nt] = *(const short8*)&Bs[wn * 64 + nt * 16 + (lane & 15)][ks * 32 + (lane >> 4) * 8];
#pragma unroll
            for (int mt = 0; mt < 4; mt++)
#pragma unroll
                for (int nt = 0; nt < 4; nt++)
                    acc[mt][nt] = __builtin_amdgcn_mfma_f32_16x16x32_bf16(
                        af[mt], bf[nt], acc[mt][nt], 0, 0, 0);
        }
        __syncthreads();
    }

    // epilogue: C/D layout col=lane&15, row=(lane>>4)*4+reg  [m89-verified]
    const float* be = bias + (size_t)e * N;
#pragma unroll
    for (int mt = 0; mt < 4; mt++) {
        int rbase = wm * 64 + mt * 16 + (lane >> 4) * 4;
#pragma unroll
        for (int nt = 0; nt < 4; nt++) {
            int gcol = nb * 128 + wn * 64 + nt * 16 + (lane & 15);
            float bv = be[gcol];
#pragma unroll
            for (int r = 0; r < 4; r++) {
                int row = rbase + r;
                int s = mb * 128 + row;
                if (s < cnt) {
                    float v = acc[mt][nt][r] + bv;
                    if (GELU) v = 0.5f * v * (1.f + erff(v * 0.70710678118654752f));
                    if constexpr (sizeof(OutT) == 2)
                        Out[(size_t)tok[row] * N + gcol] = (OutT)f2b(v);
                    else
                        Out[(size_t)tok[row] * N + gcol] = v;
                }
            }
        }
    }
}

extern "C" void kernel_launch(void* const* d_in, const int* in_sizes, int n_in,
                              void* d_out, int out_size, void* d_ws, size_t ws_size,
                              hipStream_t stream)
{
    const float* x  = (const float*)d_in[0];
    const float* wr = (const float*)d_in[1];
    const float* br = (const float*)d_in[2];
    const float* w1 = (const float*)d_in[3];
    const float* b1 = (const float*)d_in[4];
    const float* w2 = (const float*)d_in[5];
    const float* b2 = (const float*)d_in[6];
    float* out = (float*)d_out;

    char* ws = (char*)d_ws;
    int* counts    = (int*)ws;                          // 32 B
    int* top1      = (int*)(ws + 1024);                 // 32 KiB
    int* idx       = (int*)(ws + 64 * 1024);            // 256 KiB (ends 320K)
    uint16_t* xb   = (uint16_t*)(ws + ((size_t)1 << 20));   // 16 MiB
    uint16_t* hbuf = (uint16_t*)(ws + ((size_t)17 << 20));  // 64 MiB
    uint16_t* wT   = (uint16_t*)(ws + ((size_t)81 << 20));  // 32 MiB (4 experts/chunk)
    // peak ws use: 113 MiB

    hipLaunchKernelGGL(zero_counts, dim3(1), dim3(64), 0, stream, counts);
    hipLaunchKernelGGL(router_kernel, dim3(NTOK / 4), dim3(256), 0, stream,
                       x, wr, br, top1);
    hipLaunchKernelGGL(scatter_kernel, dim3(NTOK / 256), dim3(256), 0, stream,
                       top1, counts, idx);
    hipLaunchKernelGGL(convert_x_kernel, dim3(NTOK * C_ / (256 * 8)), dim3(256), 0,
                       stream, x, xb);

    // 4 experts per chunk: transpose w1 -> GEMM1, then w2 -> GEMM2
    for (int ebase = 0; ebase < E_; ebase += 4) {
        hipLaunchKernelGGL(transpose_cvt_kernel, dim3(H_ / 64, C_ / 64, 4),
                           dim3(256), 0, stream, w1, wT, C_, H_, ebase);
        hipLaunchKernelGGL((gemm_kernel<C_, H_, uint16_t, true>),
                           dim3(H_ / 128, NTOK / 128, 4), dim3(256), 0, stream,
                           xb, wT, b1, hbuf, counts, idx, ebase);
    }
    for (int ebase = 0; ebase < E_; ebase += 4) {
        hipLaunchKernelGGL(transpose_cvt_kernel, dim3(C_ / 64, H_ / 64, 4),
                           dim3(256), 0, stream, w2, wT, H_, C_, ebase);
        hipLaunchKernelGGL((gemm_kernel<H_, C_, float, false>),
                           dim3(C_ / 128, NTOK / 128, 4), dim3(256), 0, stream,
                           hbuf, wT, b2, out, counts, idx, ebase);
    }
}

// Round 3
// 773.395 us; speedup vs baseline: 1.0056x; 1.0056x over previous
//
#include <hip/hip_runtime.h>
#include <cstdint>
#include <cstddef>

#define NTOK 8192
#define C_ 1024
#define H_ 4096
#define E_ 8
#define YMAX 67   // max token-tiles per 4-expert chunk: 8192/128 + 3

typedef __attribute__((ext_vector_type(8))) short short8;
typedef __attribute__((ext_vector_type(4))) float f32x4;
typedef __attribute__((ext_vector_type(4))) unsigned int u32x4;

__device__ __forceinline__ uint16_t f2b(float f) {
    uint32_t x;
    __builtin_memcpy(&x, &f, 4);
    x = (x + 0x7fffu + ((x >> 16) & 1u)) >> 16;  // round-to-nearest-even
    return (uint16_t)x;
}

__device__ __forceinline__ void gld_lds16(const uint16_t* g, uint16_t* l) {
    __builtin_amdgcn_global_load_lds(
        (const __attribute__((address_space(1))) void*)g,
        (__attribute__((address_space(3))) void*)l, 16, 0, 0);
}

// tanh-form GELU, NaN-safe at |v| large; |err vs erf-gelu| < ~3e-3
__device__ __forceinline__ float gelu_f(float v) {
    float u = v * (0.7978845608028654f + 0.03567740814183f * v * v);
    float t = __expf(2.f * u);
    float th = 1.f - 2.f / (t + 1.f);
    return 0.5f * v * (1.f + th);
}

// ---------------- router: one wave per token, fp32 logits -> first-argmax ---
__global__ __launch_bounds__(256) void router_kernel(
    const float* __restrict__ x, const float* __restrict__ wr,
    const float* __restrict__ br, int* __restrict__ top1)
{
    int wid = threadIdx.x >> 6, lane = threadIdx.x & 63;
    int tok = blockIdx.x * 4 + wid;
    const float* xrow = x + (size_t)tok * C_;
    float acc[E_];
#pragma unroll
    for (int e = 0; e < E_; e++) acc[e] = 0.f;
#pragma unroll 4
    for (int i = 0; i < C_ / 64; i++) {
        int c = i * 64 + lane;
        float xv = xrow[c];
        const f32x4 w0 = *(const f32x4*)(wr + (size_t)c * E_);
        const f32x4 w1v = *(const f32x4*)(wr + (size_t)c * E_ + 4);
#pragma unroll
        for (int e = 0; e < 4; e++) acc[e] += xv * w0[e];
#pragma unroll
        for (int e = 0; e < 4; e++) acc[4 + e] += xv * w1v[e];
    }
#pragma unroll
    for (int off = 32; off > 0; off >>= 1) {
#pragma unroll
        for (int e = 0; e < E_; e++) acc[e] += __shfl_xor(acc[e], off, 64);
    }
    if (lane == 0) {
        float best = acc[0] + br[0];
        int bi = 0;
#pragma unroll
        for (int e = 1; e < E_; e++) {
            float v = acc[e] + br[e];
            if (v > best) { best = v; bi = e; }  // strict > == first-max (np argmax)
        }
        top1[tok] = bi;
    }
}

__global__ void zero_counts(int* counts) {
    if (threadIdx.x < E_) counts[threadIdx.x] = 0;
}

__global__ __launch_bounds__(256) void scatter_kernel(
    const int* __restrict__ top1, int* counts, int* __restrict__ idx)
{
    int t = blockIdx.x * 256 + threadIdx.x;
    int e = top1[t];
    int p = atomicAdd(&counts[e], 1);
    idx[e * NTOK + p] = t;
}

// ---------------- plan: compact (expert, mb) tile table per 4-expert chunk --
__global__ void plan_kernel(const int* __restrict__ counts,
                            int* __restrict__ tab, int* __restrict__ tabcnt)
{
    if (threadIdx.x == 0) {
        for (int c = 0; c < 2; c++) {
            int n = 0;
            for (int ez = 0; ez < 4; ez++) {
                int e = c * 4 + ez;
                int nt = (counts[e] + 127) >> 7;
                for (int mb = 0; mb < nt; mb++) tab[c * 72 + n++] = (e << 16) | mb;
            }
            tabcnt[c] = n;
        }
    }
}

// ---------------- x fp32 -> bf16 --------------------------------------------
__global__ __launch_bounds__(256) void convert_x_kernel(
    const float* __restrict__ x, uint16_t* __restrict__ xb)
{
    size_t i = ((size_t)blockIdx.x * 256 + threadIdx.x) * 8;
    f32x4 a = *(const f32x4*)(x + i);
    f32x4 b = *(const f32x4*)(x + i + 4);
    u32x4 o;
    o.x = (uint32_t)f2b(a.x) | ((uint32_t)f2b(a.y) << 16);
    o.y = (uint32_t)f2b(a.z) | ((uint32_t)f2b(a.w) << 16);
    o.z = (uint32_t)f2b(b.x) | ((uint32_t)f2b(b.y) << 16);
    o.w = (uint32_t)f2b(b.z) | ((uint32_t)f2b(b.w) << 16);
    *(u32x4*)(xb + i) = o;
}

__global__ __launch_bounds__(256) void zero_out_kernel(float* __restrict__ out)
{
    size_t i = ((size_t)blockIdx.x * 256 + threadIdx.x) * 4;
    *(f32x4*)(out + i) = (f32x4)(0.f);
}

// ------- transpose+convert: w fp32 [E][K][N] -> wt bf16 [ez][N][K] ----------
__global__ __launch_bounds__(256) void transpose_cvt_kernel(
    const float* __restrict__ w, uint16_t* __restrict__ wt,
    int K, int N, int ebase)
{
    __shared__ uint16_t tile[64][66];
    int ez = blockIdx.z, e = ebase + ez;
    int n0 = blockIdx.x * 64, k0 = blockIdx.y * 64;
    int t = threadIdx.x;
#pragma unroll
    for (int i = 0; i < 4; i++) {
        int chunk = i * 256 + t;
        int r = chunk >> 4, c4 = chunk & 15;
        f32x4 v = *(const f32x4*)(w + (size_t)(e * K + k0 + r) * N + n0 + c4 * 4);
        uint32_t u0 = (uint32_t)f2b(v.x) | ((uint32_t)f2b(v.y) << 16);
        uint32_t u1 = (uint32_t)f2b(v.z) | ((uint32_t)f2b(v.w) << 16);
        *(uint32_t*)&tile[r][c4 * 4 + 0] = u0;
        *(uint32_t*)&tile[r][c4 * 4 + 2] = u1;
    }
    __syncthreads();
#pragma unroll
    for (int i = 0; i < 2; i++) {
        int chunk = i * 256 + t;
        int rn = chunk >> 3, ck = chunk & 7;
        uint32_t p[4];
#pragma unroll
        for (int j = 0; j < 4; j++) {
            uint32_t lo = tile[ck * 8 + 2 * j][rn];
            uint32_t hi = tile[ck * 8 + 2 * j + 1][rn];
            p[j] = lo | (hi << 16);
        }
        u32x4 v; v.x = p[0]; v.y = p[1]; v.z = p[2]; v.w = p[3];
        *(u32x4*)(wt + ((size_t)ez * N + n0 + rn) * K + k0 + ck * 8) = v;
    }
}

// ---------------- grouped GEMM (m97 structure, compacted tiles) -------------
// A bf16 [NTOK][LDA], rows gathered by token id; Bt bf16 [ez][N][LDB], k contig
// KSTEP = K per block (blockIdx.z selects K-slice for split-K).
// ATOMIC: fp32 atomicAdd into Out (bias applied only on z==0).
template <int KSTEP, int LDA, int LDB, int N, typename OutT, bool GELU, bool ATOMIC>
__global__ __launch_bounds__(256) void gemm_kernel(
    const uint16_t* __restrict__ A, const uint16_t* __restrict__ Bt,
    const float* __restrict__ bias, OutT* __restrict__ Out,
    const int* __restrict__ counts, const int* __restrict__ idx,
    const int* __restrict__ tab, const int* __restrict__ tabcnt,
    int chunk, int ebase)
{
    int tile = blockIdx.y;
    if (tile >= tabcnt[chunk]) return;          // contiguous dead tail only
    int ent = tab[chunk * 72 + tile];
    int e = ent >> 16, mb = ent & 0xffff;
    int ez = e - ebase;
    int cnt = counts[e];
    int nb = blockIdx.x;
    int kbase = blockIdx.z * KSTEP;

    __shared__ __align__(16) uint16_t As[128][64];
    __shared__ __align__(16) uint16_t Bs[128][64];
    __shared__ int tok[128];

    int t = threadIdx.x;
    const int* idxe = idx + e * NTOK;
    if (t < 128) {
        int s = mb * 128 + t;
        tok[t] = idxe[(s < cnt) ? s : 0];
    }
    __syncthreads();

    int lane = t & 63, w = t >> 6;
    int wm = w >> 1, wn = w & 1;

    f32x4 acc[4][4];
#pragma unroll
    for (int mt = 0; mt < 4; mt++)
#pragma unroll
        for (int nt = 0; nt < 4; nt++) acc[mt][nt] = (f32x4)(0.f);

    const uint16_t* Bte = Bt + ((size_t)ez * N + (size_t)nb * 128) * LDB + kbase;
    uint16_t* As0 = &As[0][0];
    uint16_t* Bs0 = &Bs[0][0];

    const uint16_t* aptr[4];
    const uint16_t* bptr[4];
#pragma unroll
    for (int i = 0; i < 4; i++) {
        int chunkid = i * 256 + w * 64 + lane;
        int r = chunkid >> 3, kc = chunkid & 7;
        aptr[i] = A + (size_t)tok[r] * LDA + kbase + kc * 8;
        bptr[i] = Bte + (size_t)r * LDB + kc * 8;
    }

    for (int kt = 0; kt < KSTEP / 64; kt++) {
        int k0 = kt * 64;
#pragma unroll
        for (int i = 0; i < 4; i++)
            gld_lds16(aptr[i] + k0, As0 + (size_t)(i * 256 + w * 64) * 8);
#pragma unroll
        for (int i = 0; i < 4; i++)
            gld_lds16(bptr[i] + k0, Bs0 + (size_t)(i * 256 + w * 64) * 8);
        __syncthreads();
#pragma unroll
        for (int ks = 0; ks < 2; ks++) {
            short8 af[4], bf[4];
#pragma unroll
            for (int mt = 0; mt < 4; mt++)
                af[mt] = *(const short8*)&As[wm * 64 + mt * 16 + (lane & 15)][ks * 32 + (lane >> 4) * 8];
#pragma unroll
            for (int nt = 0; nt < 4; nt++)
                bf[nt] = *(const short8*)&Bs[wn * 64 + nt * 16 + (lane & 15)][ks * 32 + (lane >> 4) * 8];
#pragma unroll
            for (int mt = 0; mt < 4; mt++)
#pragma unroll
                for (int nt = 0; nt < 4; nt++)
                    acc[mt][nt] = __builtin_amdgcn_mfma_f32_16x16x32_bf16(
                        af[mt], bf[nt], acc[mt][nt], 0, 0, 0);
        }
        __syncthreads();
    }

    // epilogue: C/D layout col=lane&15, row=(lane>>4)*4+reg  [m89-verified]
    const float* be = bias + (size_t)e * N;
#pragma unroll
    for (int mt = 0; mt < 4; mt++) {
        int rbase = wm * 64 + mt * 16 + (lane >> 4) * 4;
#pragma unroll
        for (int nt = 0; nt < 4; nt++) {
            int gcol = nb * 128 + wn * 64 + nt * 16 + (lane & 15);
            float bv = be[gcol];
#pragma unroll
            for (int r = 0; r < 4; r++) {
                int row = rbase + r;
                int s = mb * 128 + row;
                if (s < cnt) {
                    float v = acc[mt][nt][r];
                    if constexpr (ATOMIC) {
                        if (blockIdx.z == 0) v += bv;
                        atomicAdd(&Out[(size_t)tok[row] * N + gcol], (OutT)v);
                    } else {
                        v += bv;
                        if (GELU) v = gelu_f(v);
                        Out[(size_t)tok[row] * N + gcol] = (OutT)f2b(v);
                    }
                }
            }
        }
    }
}

extern "C" void kernel_launch(void* const* d_in, const int* in_sizes, int n_in,
                              void* d_out, int out_size, void* d_ws, size_t ws_size,
                              hipStream_t stream)
{
    const float* x  = (const float*)d_in[0];
    const float* wr = (const float*)d_in[1];
    const float* br = (const float*)d_in[2];
    const float* w1 = (const float*)d_in[3];
    const float* b1 = (const float*)d_in[4];
    const float* w2 = (const float*)d_in[5];
    const float* b2 = (const float*)d_in[6];
    float* out = (float*)d_out;

    char* ws = (char*)d_ws;
    int* counts    = (int*)ws;                          // 32 B
    int* top1      = (int*)(ws + 1024);                 // 32 KiB
    int* idx       = (int*)(ws + 64 * 1024);            // 256 KiB
    int* tab       = (int*)(ws + 384 * 1024);           // 2*72 ints
    int* tabcnt    = (int*)(ws + 400 * 1024);           // 2 ints
    uint16_t* xb   = (uint16_t*)(ws + ((size_t)1 << 20));   // 16 MiB
    uint16_t* hbuf = (uint16_t*)(ws + ((size_t)17 << 20));  // 64 MiB
    uint16_t* wT   = (uint16_t*)(ws + ((size_t)81 << 20));  // 32 MiB (4 experts)
    // peak ws use: 113 MiB

    hipLaunchKernelGGL(zero_counts, dim3(1), dim3(64), 0, stream, counts);
    hipLaunchKernelGGL(router_kernel, dim3(NTOK / 4), dim3(256), 0, stream,
                       x, wr, br, top1);
    hipLaunchKernelGGL(scatter_kernel, dim3(NTOK / 256), dim3(256), 0, stream,
                       top1, counts, idx);
    hipLaunchKernelGGL(plan_kernel, dim3(1), dim3(64), 0, stream,
                       counts, tab, tabcnt);
    hipLaunchKernelGGL(convert_x_kernel, dim3(NTOK * C_ / (256 * 8)), dim3(256), 0,
                       stream, x, xb);

    // GEMM1: h = gelu(x @ w1 + b1), bf16 out, 4 experts per chunk
    for (int c = 0; c < 2; c++) {
        hipLaunchKernelGGL(transpose_cvt_kernel, dim3(H_ / 64, C_ / 64, 4),
                           dim3(256), 0, stream, w1, wT, C_, H_, c * 4);
        hipLaunchKernelGGL((gemm_kernel<1024, C_, C_, H_, uint16_t, true, false>),
                           dim3(H_ / 128, YMAX, 1), dim3(256), 0, stream,
                           xb, wT, b1, hbuf, counts, idx, tab, tabcnt, c, c * 4);
    }

    // GEMM2: out = h @ w2 + b2, fp32 atomics with split-K = 4
    hipLaunchKernelGGL(zero_out_kernel, dim3(NTOK * C_ / (256 * 4)), dim3(256), 0,
                       stream, out);
    for (int c = 0; c < 2; c++) {
        hipLaunchKernelGGL(transpose_cvt_kernel, dim3(C_ / 64, H_ / 64, 4),
                           dim3(256), 0, stream, w2, wT, H_, C_, c * 4);
        hipLaunchKernelGGL((gemm_kernel<1024, H_, H_, C_, float, false, true>),
                           dim3(C_ / 128, YMAX, 4), dim3(256), 0, stream,
                           hbuf, wT, b2, out, counts, idx, tab, tabcnt, c, c * 4);
    }
}

// Round 4
// 769.756 us; speedup vs baseline: 1.0104x; 1.0047x over previous
//
#include <hip/hip_runtime.h>
#include <cstdint>
#include <cstddef>

#define NTOK 8192
#define C_ 1024
#define H_ 4096
#define E_ 8
#define YMAX 72   // max tiles over all 8 experts: 8192/128 + 8 pad

typedef __attribute__((ext_vector_type(8))) short short8;
typedef __attribute__((ext_vector_type(4))) float f32x4;
typedef __attribute__((ext_vector_type(4))) unsigned int u32x4;

__device__ __forceinline__ uint16_t f2b(float f) {
    uint32_t x;
    __builtin_memcpy(&x, &f, 4);
    x = (x + 0x7fffu + ((x >> 16) & 1u)) >> 16;  // round-to-nearest-even
    return (uint16_t)x;
}

__device__ __forceinline__ void gld_lds16(const uint16_t* g, uint16_t* l) {
    __builtin_amdgcn_global_load_lds(
        (const __attribute__((address_space(1))) void*)g,
        (__attribute__((address_space(3))) void*)l, 16, 0, 0);
}

// tanh-form GELU, NaN-safe; |err vs erf-gelu| < ~3e-3 (threshold headroom 0.04)
__device__ __forceinline__ float gelu_f(float v) {
    float u = v * (0.7978845608028654f + 0.03567740814183f * v * v);
    float t = __expf(2.f * u);
    float th = 1.f - 2.f / (t + 1.f);
    return 0.5f * v * (1.f + th);
}

// ---------------- router: one wave per token, fp32 logits -> first-argmax ---
__global__ __launch_bounds__(256) void router_kernel(
    const float* __restrict__ x, const float* __restrict__ wr,
    const float* __restrict__ br, int* __restrict__ top1)
{
    int wid = threadIdx.x >> 6, lane = threadIdx.x & 63;
    int tok = blockIdx.x * 4 + wid;
    const float* xrow = x + (size_t)tok * C_;
    float acc[E_];
#pragma unroll
    for (int e = 0; e < E_; e++) acc[e] = 0.f;
#pragma unroll 4
    for (int i = 0; i < C_ / 64; i++) {
        int c = i * 64 + lane;
        float xv = xrow[c];
        const f32x4 w0 = *(const f32x4*)(wr + (size_t)c * E_);
        const f32x4 w1v = *(const f32x4*)(wr + (size_t)c * E_ + 4);
#pragma unroll
        for (int e = 0; e < 4; e++) acc[e] += xv * w0[e];
#pragma unroll
        for (int e = 0; e < 4; e++) acc[4 + e] += xv * w1v[e];
    }
#pragma unroll
    for (int off = 32; off > 0; off >>= 1) {
#pragma unroll
        for (int e = 0; e < E_; e++) acc[e] += __shfl_xor(acc[e], off, 64);
    }
    if (lane == 0) {
        float best = acc[0] + br[0];
        int bi = 0;
#pragma unroll
        for (int e = 1; e < E_; e++) {
            float v = acc[e] + br[e];
            if (v > best) { best = v; bi = e; }  // strict > == first-max (np argmax)
        }
        top1[tok] = bi;
    }
}

__global__ void zero_counts(int* counts) {
    if (threadIdx.x < E_) counts[threadIdx.x] = 0;
}

__global__ __launch_bounds__(256) void scatter_kernel(
    const int* __restrict__ top1, int* counts, int* __restrict__ idx)
{
    int t = blockIdx.x * 256 + threadIdx.x;
    int e = top1[t];
    int p = atomicAdd(&counts[e], 1);
    idx[e * NTOK + p] = t;
}

// ---- plan: compact (expert, mb) tile table + ranges {full, chunk0, chunk1} -
__global__ void plan_kernel(const int* __restrict__ counts,
                            int* __restrict__ tab, int* __restrict__ ranges)
{
    if (threadIdx.x == 0) {
        int n = 0, n0 = 0;
        for (int e = 0; e < E_; e++) {
            int nt = (counts[e] + 127) >> 7;
            for (int mb = 0; mb < nt; mb++) tab[n++] = (e << 16) | mb;
            if (e == 3) n0 = n;
        }
        ranges[0] = 0;  ranges[1] = n;   // all 8 experts
        ranges[2] = 0;  ranges[3] = n0;  // experts 0..3
        ranges[4] = n0; ranges[5] = n;   // experts 4..7
    }
}

// ---------------- x fp32 -> bf16 --------------------------------------------
__global__ __launch_bounds__(256) void convert_x_kernel(
    const float* __restrict__ x, uint16_t* __restrict__ xb)
{
    size_t i = ((size_t)blockIdx.x * 256 + threadIdx.x) * 8;
    f32x4 a = *(const f32x4*)(x + i);
    f32x4 b = *(const f32x4*)(x + i + 4);
    u32x4 o;
    o.x = (uint32_t)f2b(a.x) | ((uint32_t)f2b(a.y) << 16);
    o.y = (uint32_t)f2b(a.z) | ((uint32_t)f2b(a.w) << 16);
    o.z = (uint32_t)f2b(b.x) | ((uint32_t)f2b(b.y) << 16);
    o.w = (uint32_t)f2b(b.z) | ((uint32_t)f2b(b.w) << 16);
    *(u32x4*)(xb + i) = o;
}

// ------- transpose+convert: w fp32 [E][K][N] -> wt bf16 [ez][N][K] ----------
__global__ __launch_bounds__(256) void transpose_cvt_kernel(
    const float* __restrict__ w, uint16_t* __restrict__ wt,
    int K, int N, int ebase)
{
    __shared__ uint16_t tile[64][66];
    int ez = blockIdx.z, e = ebase + ez;
    int n0 = blockIdx.x * 64, k0 = blockIdx.y * 64;
    int t = threadIdx.x;
#pragma unroll
    for (int i = 0; i < 4; i++) {
        int chunk = i * 256 + t;
        int r = chunk >> 4, c4 = chunk & 15;
        f32x4 v = *(const f32x4*)(w + (size_t)(e * K + k0 + r) * N + n0 + c4 * 4);
        uint32_t u0 = (uint32_t)f2b(v.x) | ((uint32_t)f2b(v.y) << 16);
        uint32_t u1 = (uint32_t)f2b(v.z) | ((uint32_t)f2b(v.w) << 16);
        *(uint32_t*)&tile[r][c4 * 4 + 0] = u0;
        *(uint32_t*)&tile[r][c4 * 4 + 2] = u1;
    }
    __syncthreads();
#pragma unroll
    for (int i = 0; i < 2; i++) {
        int chunk = i * 256 + t;
        int rn = chunk >> 3, ck = chunk & 7;
        uint32_t p[4];
#pragma unroll
        for (int j = 0; j < 4; j++) {
            uint32_t lo = tile[ck * 8 + 2 * j][rn];
            uint32_t hi = tile[ck * 8 + 2 * j + 1][rn];
            p[j] = lo | (hi << 16);
        }
        u32x4 v; v.x = p[0]; v.y = p[1]; v.z = p[2]; v.w = p[3];
        *(u32x4*)(wt + ((size_t)ez * N + n0 + rn) * K + k0 + ck * 8) = v;
    }
}

// ---------------- grouped GEMM, full-K, XOR-swizzled LDS --------------------
// A bf16 [NTOK][K] gathered by token id; Bt bf16 [ez][N][K] k-contig.
// Tile 128M x TN(128/256)N. LDS chunk j of each 64-elem row holds global
// chunk j^(row&7)  ->  fragment reads hit 2 lanes/bank (free, m136).
template <int K, int N, int TN, typename OutT, bool GELU>
__global__ __launch_bounds__(256) void gemm_kernel(
    const uint16_t* __restrict__ A, const uint16_t* __restrict__ Bt,
    const float* __restrict__ bias, OutT* __restrict__ Out,
    const int* __restrict__ counts, const int* __restrict__ idx,
    const int* __restrict__ tab, const int* __restrict__ range, int ebase)
{
    constexpr int NT = TN / 32;   // n-frags per wave (4 or 8)
    constexpr int BI = TN / 32;   // B staging insts per wave (4 or 8)

    int tile = range[0] + blockIdx.y;
    if (tile >= range[1]) return;
    int ent = tab[tile];
    int e = ent >> 16, mb = ent & 0xffff;
    int ez = e - ebase;
    int cnt = counts[e];
    int nb = blockIdx.x;

    __shared__ __align__(16) uint16_t As[128][64];
    __shared__ __align__(16) uint16_t Bs[TN][64];
    __shared__ int tok[128];

    int t = threadIdx.x;
    const int* idxe = idx + e * NTOK;
    if (t < 128) {
        int s = mb * 128 + t;
        tok[t] = idxe[(s < cnt) ? s : 0];
    }
    __syncthreads();

    int lane = t & 63, w = t >> 6;
    int wm = w >> 1, wn = w & 1;

    f32x4 acc[4][NT];
#pragma unroll
    for (int mt = 0; mt < 4; mt++)
#pragma unroll
        for (int nt = 0; nt < NT; nt++) acc[mt][nt] = (f32x4)(0.f);

    const uint16_t* Bte = Bt + ((size_t)ez * N + (size_t)nb * TN) * K;
    uint16_t* As0 = &As[0][0];
    uint16_t* Bs0 = &Bs[0][0];

    // staging pointers: physical LDS chunk j <- global chunk j^(r&7)
    const uint16_t* aptr[4];
    const uint16_t* bptr[BI];
#pragma unroll
    for (int i = 0; i < 4; i++) {
        int cid = i * 256 + w * 64 + lane;
        int r = cid >> 3, j = cid & 7;
        aptr[i] = A + (size_t)tok[r] * K + (j ^ (r & 7)) * 8;
    }
#pragma unroll
    for (int i = 0; i < BI; i++) {
        int cid = i * 256 + w * 64 + lane;
        int r = cid >> 3, j = cid & 7;
        bptr[i] = Bte + (size_t)r * K + (j ^ (r & 7)) * 8;
    }

#pragma unroll 2
    for (int kt = 0; kt < K / 64; kt++) {
        int k0 = kt * 64;
#pragma unroll
        for (int i = 0; i < 4; i++)
            gld_lds16(aptr[i] + k0, As0 + (size_t)(i * 256 + w * 64) * 8);
#pragma unroll
        for (int i = 0; i < BI; i++)
            gld_lds16(bptr[i] + k0, Bs0 + (size_t)(i * 256 + w * 64) * 8);
        __syncthreads();
#pragma unroll
        for (int ks = 0; ks < 2; ks++) {
            int cs = ((ks << 2) + (lane >> 4)) ^ (lane & 7);  // swizzled chunk
            short8 af[4], bfr[NT];
#pragma unroll
            for (int mt = 0; mt < 4; mt++)
                af[mt] = *(const short8*)&As[wm * 64 + mt * 16 + (lane & 15)][cs * 8];
#pragma unroll
            for (int nt = 0; nt < NT; nt++)
                bfr[nt] = *(const short8*)&Bs[wn * (TN / 2) + nt * 16 + (lane & 15)][cs * 8];
#pragma unroll
            for (int mt = 0; mt < 4; mt++)
#pragma unroll
                for (int nt = 0; nt < NT; nt++)
                    acc[mt][nt] = __builtin_amdgcn_mfma_f32_16x16x32_bf16(
                        af[mt], bfr[nt], acc[mt][nt], 0, 0, 0);
        }
        __syncthreads();
    }

    // epilogue: C/D layout col=lane&15, row=(lane>>4)*4+reg  [m89-verified]
    const float* be = bias + (size_t)e * N;
#pragma unroll
    for (int mt = 0; mt < 4; mt++) {
        int rbase = wm * 64 + mt * 16 + (lane >> 4) * 4;
#pragma unroll
        for (int nt = 0; nt < NT; nt++) {
            int gcol = nb * TN + wn * (TN / 2) + nt * 16 + (lane & 15);
            float bv = be[gcol];
#pragma unroll
            for (int r = 0; r < 4; r++) {
                int row = rbase + r;
                int s = mb * 128 + row;
                if (s < cnt) {
                    float v = acc[mt][nt][r] + bv;
                    if (GELU) v = gelu_f(v);
                    if constexpr (sizeof(OutT) == 2)
                        Out[(size_t)tok[row] * N + gcol] = (OutT)f2b(v);
                    else
                        Out[(size_t)tok[row] * N + gcol] = v;
                }
            }
        }
    }
}

extern "C" void kernel_launch(void* const* d_in, const int* in_sizes, int n_in,
                              void* d_out, int out_size, void* d_ws, size_t ws_size,
                              hipStream_t stream)
{
    const float* x  = (const float*)d_in[0];
    const float* wr = (const float*)d_in[1];
    const float* br = (const float*)d_in[2];
    const float* b1 = (const float*)d_in[4];
    const float* w1 = (const float*)d_in[3];
    const float* w2 = (const float*)d_in[5];
    const float* b2 = (const float*)d_in[6];
    float* out = (float*)d_out;

    char* ws = (char*)d_ws;
    int* counts    = (int*)ws;                          // 32 B
    int* top1      = (int*)(ws + 1024);                 // 32 KiB
    int* idx       = (int*)(ws + 64 * 1024);            // 256 KiB
    int* tab       = (int*)(ws + 384 * 1024);           // 72 ints
    int* ranges    = (int*)(ws + 400 * 1024);           // 6 ints
    uint16_t* xb   = (uint16_t*)(ws + ((size_t)1 << 20));   // 16 MiB
    uint16_t* hbuf = (uint16_t*)(ws + ((size_t)17 << 20));  // 64 MiB
    uint16_t* wT   = (uint16_t*)(ws + ((size_t)81 << 20));  // 64 MiB (big) / 32 MiB

    // big path needs 81 + 64 = 145 MiB of ws; fallback (113 MiB) is proven.
    bool big = ws_size >= ((size_t)145 << 20);

    hipLaunchKernelGGL(zero_counts, dim3(1), dim3(64), 0, stream, counts);
    hipLaunchKernelGGL(router_kernel, dim3(NTOK / 4), dim3(256), 0, stream,
                       x, wr, br, top1);
    hipLaunchKernelGGL(scatter_kernel, dim3(NTOK / 256), dim3(256), 0, stream,
                       top1, counts, idx);
    hipLaunchKernelGGL(plan_kernel, dim3(1), dim3(64), 0, stream,
                       counts, tab, ranges);
    hipLaunchKernelGGL(convert_x_kernel, dim3(NTOK * C_ / (256 * 8)), dim3(256), 0,
                       stream, x, xb);

    if (big) {
        // GEMM1: h = gelu(x @ w1 + b1), one dispatch, 128x256 tiles
        hipLaunchKernelGGL(transpose_cvt_kernel, dim3(H_ / 64, C_ / 64, E_),
                           dim3(256), 0, stream, w1, wT, C_, H_, 0);
        hipLaunchKernelGGL((gemm_kernel<C_, H_, 256, uint16_t, true>),
                           dim3(H_ / 256, YMAX, 1), dim3(256), 0, stream,
                           xb, wT, b1, hbuf, counts, idx, tab, ranges + 0, 0);
        // GEMM2: out = h @ w2 + b2, one dispatch, full K=4096, plain stores
        hipLaunchKernelGGL(transpose_cvt_kernel, dim3(C_ / 64, H_ / 64, E_),
                           dim3(256), 0, stream, w2, wT, H_, C_, 0);
        hipLaunchKernelGGL((gemm_kernel<H_, C_, 128, float, false>),
                           dim3(C_ / 128, YMAX, 1), dim3(256), 0, stream,
                           hbuf, wT, b2, out, counts, idx, tab, ranges + 0, 0);
    } else {
        for (int c = 0; c < 2; c++) {
            hipLaunchKernelGGL(transpose_cvt_kernel, dim3(H_ / 64, C_ / 64, 4),
                               dim3(256), 0, stream, w1, wT, C_, H_, c * 4);
            hipLaunchKernelGGL((gemm_kernel<C_, H_, 256, uint16_t, true>),
                               dim3(H_ / 256, YMAX, 1), dim3(256), 0, stream,
                               xb, wT, b1, hbuf, counts, idx, tab, ranges + 2 + 2 * c, c * 4);
        }
        for (int c = 0; c < 2; c++) {
            hipLaunchKernelGGL(transpose_cvt_kernel, dim3(C_ / 64, H_ / 64, 4),
                               dim3(256), 0, stream, w2, wT, H_, C_, c * 4);
            hipLaunchKernelGGL((gemm_kernel<H_, C_, 128, float, false>),
                               dim3(C_ / 128, YMAX, 1), dim3(256), 0, stream,
                               hbuf, wT, b2, out, counts, idx, tab, ranges + 2 + 2 * c, c * 4);
        }
    }
}